// Round 6
// baseline (109.889 us; speedup 1.0000x reference)
//
#include <hip/hip_runtime.h>
#include <hip/hip_bf16.h>

#define DIM 32
#define LOG_NPB 7
#define NPB 128              // nodes per bucket
#define CAP 4096             // edge capacity per bucket (avg ~2046)
#define NBINS 800            // >= ceil(100000/128)=782
#define EPB 4096             // edges per scatter block
#define EPT 16               // edges per thread in scatter (EPB/256)

// ---------------------------------------------------------------------------
// Kernel 1: out = x @ W2^T + b2 (fp32) ;  y = x @ W1^T (bf16, packed stores)
// ---------------------------------------------------------------------------
__global__ __launch_bounds__(256) void fused_lin_kernel(
    const float* __restrict__ x,
    const float* __restrict__ W1,
    const float* __restrict__ W2,
    const float* __restrict__ b2,
    float* __restrict__ out,
    unsigned* __restrict__ y32,   // y as packed bf16x2
    int n_nodes)
{
    __shared__ float W1s[DIM][DIM];
    __shared__ float W2s[DIM][DIM];
    __shared__ float b2s[DIM];
    __shared__ float xs[8][DIM];

    const int t = threadIdx.x;
    for (int i = t; i < DIM * DIM; i += 256) {
        int c = i >> 5, k = i & 31;
        W1s[k][c] = W1[i];
        W2s[k][c] = W2[i];
    }
    if (t < DIM) b2s[t] = b2[t];

    const int r = t >> 5;
    const int c = t & 31;
    const int ntiles = (n_nodes + 7) >> 3;

    for (int tile = blockIdx.x; tile < ntiles; tile += gridDim.x) {
        const int row = tile * 8 + r;
        __syncthreads();
        if (row < n_nodes) xs[r][c] = x[(long)row * DIM + c];
        __syncthreads();
        if (row < n_nodes) {
            float a2 = b2s[c];
            float a1 = 0.0f;
            #pragma unroll
            for (int k = 0; k < DIM; ++k) {
                float xv = xs[r][k];
                a2 += xv * W2s[k][c];
                a1 += xv * W1s[k][c];
            }
            out[(long)row * DIM + c] = a2;
            // pack two bf16 per u32 store (lanes c, c+1 of same row)
            float hi = __shfl_down(a1, 1);
            if ((c & 1) == 0) {
                __hip_bfloat16 blo = __float2bfloat16(a1);
                __hip_bfloat16 bhi = __float2bfloat16(hi);
                unsigned pack = ((unsigned)(*(unsigned short*)&bhi) << 16)
                              | (unsigned)(*(unsigned short*)&blo);
                y32[(size_t)row * 16 + (c >> 1)] = pack;
            }
        }
    }
}

__global__ __launch_bounds__(256) void init_cursor_kernel(int* __restrict__ cursor, int nb)
{
    int i = blockIdx.x * 256 + threadIdx.x;
    if (i < nb) cursor[i] = i * CAP;
}

// ---------------------------------------------------------------------------
// Pass 1: bucket scatter with block-level LDS aggregation (782 buckets).
// ---------------------------------------------------------------------------
__global__ __launch_bounds__(256) void bucket_scatter_kernel(
    const int* __restrict__ src, const int* __restrict__ dst,
    int* __restrict__ cursor, unsigned* __restrict__ bedges, int nE)
{
    __shared__ int cnt[NBINS];
    __shared__ int base[NBINS];
    __shared__ int rank[NBINS];

    const int t = threadIdx.x;
    const long blockStart = (long)blockIdx.x * EPB;

    for (int i = t; i < NBINS; i += 256) { cnt[i] = 0; rank[i] = 0; }
    __syncthreads();

    int es[EPT], ed[EPT];
    #pragma unroll
    for (int i = 0; i < EPT; ++i) {
        long e = blockStart + i * 256 + t;
        if (e < nE) { es[i] = src[e]; ed[i] = dst[e]; }
        else        { es[i] = -1;     ed[i] = 0;      }
    }
    #pragma unroll
    for (int i = 0; i < EPT; ++i) {
        if (es[i] >= 0) atomicAdd(&cnt[ed[i] >> LOG_NPB], 1);
    }
    __syncthreads();

    for (int i = t; i < NBINS; i += 256) {
        int c = cnt[i];
        if (c > 0) base[i] = atomicAdd(&cursor[i], c);
    }
    __syncthreads();

    #pragma unroll
    for (int i = 0; i < EPT; ++i) {
        if (es[i] >= 0) {
            int b = ed[i] >> LOG_NPB;
            int r = atomicAdd(&rank[b], 1);
            int p = base[b] + r;
            if (p < (b + 1) * CAP)
                bedges[p] = ((unsigned)es[i] << LOG_NPB) | (unsigned)(ed[i] & (NPB - 1));
        }
    }
}

// ---------------------------------------------------------------------------
// Pass 2: in-bucket sort to node granularity (one block per bucket).
// ---------------------------------------------------------------------------
__global__ __launch_bounds__(256) void bucket_sort_kernel(
    const int* __restrict__ cursor, unsigned* __restrict__ bedges,
    int* __restrict__ row_start, int* __restrict__ row_cnt, int n_nodes)
{
    __shared__ unsigned ent[CAP];     // 16 KB
    __shared__ int cnt[NPB];
    __shared__ int ex[NPB];
    __shared__ int cur[NPB];

    const int b = blockIdx.x;
    const int t = threadIdx.x;
    const int start = b * CAP;
    int n = cursor[b] - start;
    if (n > CAP) n = CAP;
    if (n < 0) n = 0;

    if (t < NPB) { cnt[t] = 0; cur[t] = 0; }
    __syncthreads();

    for (int i = t; i < n; i += 256) {
        unsigned e = bedges[start + i];
        ent[i] = e;
        atomicAdd(&cnt[e & (NPB - 1)], 1);
    }
    __syncthreads();

    if (t < NPB) ex[t] = cnt[t];
    __syncthreads();
    for (int off = 1; off < NPB; off <<= 1) {
        int add = 0;
        if (t < NPB && t >= off) add = ex[t - off];
        __syncthreads();
        if (t < NPB) ex[t] += add;
        __syncthreads();
    }
    if (t < NPB) ex[t] -= cnt[t];
    __syncthreads();

    for (int i = t; i < n; i += 256) {
        unsigned e = ent[i];
        int bin = (int)(e & (NPB - 1));
        int r = atomicAdd(&cur[bin], 1);
        bedges[start + ex[bin] + r] = e >> LOG_NPB;
    }

    if (t < NPB) {
        int node = b * NPB + t;
        if (node < n_nodes) {
            row_start[node] = start + ex[t];
            row_cnt[node]   = cnt[t];
        }
    }
}

// ---------------------------------------------------------------------------
// Pass 3: gather. One wave per node; 8 slots x 8 lanes; each lane loads
// ushort4 (4 dims). 16 edges in flight per wave. No atomics.
// ---------------------------------------------------------------------------
__global__ __launch_bounds__(256) void gather_kernel(
    const int* __restrict__ row_start, const int* __restrict__ row_cnt,
    const unsigned* __restrict__ bedges, const unsigned short* __restrict__ yb,
    float* __restrict__ out, int n_nodes)
{
    const int wid  = (blockIdx.x * 256 + threadIdx.x) >> 6;   // node id
    const int lane = threadIdx.x & 63;
    if (wid >= n_nodes) return;

    const int start = row_start[wid];
    const int end   = start + row_cnt[wid];
    const int slot = lane >> 3;   // 0..7: edge slot
    const int li   = lane & 7;    // dims li*4 .. li*4+3

    float a0 = 0.f, a1 = 0.f, a2 = 0.f, a3 = 0.f;

    for (int e0 = start + slot; e0 < end; e0 += 16) {
        int e1 = e0 + 8;
        int s0 = (int)bedges[e0];
        int s1 = (int)bedges[e1 < end ? e1 : end - 1];     // clamped, unguarded
        ushort4 u0 = *(const ushort4*)(yb + ((size_t)s0 << 5) + (li << 2));
        ushort4 u1 = *(const ushort4*)(yb + ((size_t)s1 << 5) + (li << 2));
        a0 += __uint_as_float((unsigned)u0.x << 16);
        a1 += __uint_as_float((unsigned)u0.y << 16);
        a2 += __uint_as_float((unsigned)u0.z << 16);
        a3 += __uint_as_float((unsigned)u0.w << 16);
        if (e1 < end) {
            a0 += __uint_as_float((unsigned)u1.x << 16);
            a1 += __uint_as_float((unsigned)u1.y << 16);
            a2 += __uint_as_float((unsigned)u1.z << 16);
            a3 += __uint_as_float((unsigned)u1.w << 16);
        }
    }

    // reduce across the 8 slots
    #pragma unroll
    for (int m = 8; m < 64; m <<= 1) {
        a0 += __shfl_xor(a0, m);
        a1 += __shfl_xor(a1, m);
        a2 += __shfl_xor(a2, m);
        a3 += __shfl_xor(a3, m);
    }

    if (slot == 0) {
        float4* orow = (float4*)(out + ((size_t)wid << 5));
        float4 o = orow[li];
        o.x += a0; o.y += a1; o.z += a2; o.w += a3;
        orow[li] = o;
    }
}

extern "C" void kernel_launch(void* const* d_in, const int* in_sizes, int n_in,
                              void* d_out, int out_size, void* d_ws, size_t ws_size,
                              hipStream_t stream) {
    const float* x  = (const float*)d_in[0];
    const float* W1 = (const float*)d_in[1];
    const float* W2 = (const float*)d_in[2];
    const float* b2 = (const float*)d_in[3];
    const int*   ei = (const int*)d_in[4];

    const int n_nodes = in_sizes[0] / DIM;   // 100000
    const int n_edges = in_sizes[4] / 2;     // 1,600,000
    const int* src = ei;
    const int* dst = ei + n_edges;
    float* out = (float*)d_out;

    const int nb = (n_nodes + NPB - 1) / NPB;    // 782

    char* basep = (char*)d_ws;
    size_t off = 0;
    auto alloc = [&](size_t bytes) {
        char* p = basep + off;
        off = (off + bytes + 255) & ~(size_t)255;
        return p;
    };
    unsigned*       y32    = (unsigned*)alloc((size_t)n_nodes * DIM * sizeof(unsigned short));
    int*            cursor = (int*)     alloc((size_t)nb * sizeof(int));
    unsigned*       bedges = (unsigned*)alloc((size_t)nb * CAP * sizeof(unsigned));
    int*            rowst  = (int*)     alloc((size_t)n_nodes * sizeof(int));
    int*            rowcnt = (int*)     alloc((size_t)n_nodes * sizeof(int));
    (void)ws_size;

    fused_lin_kernel<<<1024, 256, 0, stream>>>(x, W1, W2, b2, out, y32, n_nodes);
    init_cursor_kernel<<<(nb + 255) / 256, 256, 0, stream>>>(cursor, nb);
    bucket_scatter_kernel<<<(n_edges + EPB - 1) / EPB, 256, 0, stream>>>(src, dst, cursor, bedges, n_edges);
    bucket_sort_kernel<<<nb, 256, 0, stream>>>(cursor, bedges, rowst, rowcnt, n_nodes);
    gather_kernel<<<(n_nodes * 64 + 255) / 256, 256, 0, stream>>>(rowst, rowcnt, bedges,
                                                                  (const unsigned short*)y32, out, n_nodes);
}

// Round 7
// 101.331 us; speedup vs baseline: 1.0845x; 1.0845x over previous
//
#include <hip/hip_runtime.h>
#include <hip/hip_bf16.h>

#define DIM 32
#define LOG_NPB 7
#define NPB 128              // nodes per bucket
#define CAP 4096             // edge capacity per bucket (avg ~2046)
#define NBINS 800            // >= ceil(100000/128)=782
#define EPB 4096             // edges per scatter block
#define EPT 16               // edges per thread in scatter (EPB/256)
#define GATHER_BLOCKS 2048   // persistent gather waves: 2048*4 = 8192

// ---------------------------------------------------------------------------
// Kernel 1: out = x @ W2^T + b2 (fp32) ;  y = x @ W1^T (bf16, packed stores)
// ---------------------------------------------------------------------------
__global__ __launch_bounds__(256) void fused_lin_kernel(
    const float* __restrict__ x,
    const float* __restrict__ W1,
    const float* __restrict__ W2,
    const float* __restrict__ b2,
    float* __restrict__ out,
    unsigned* __restrict__ y32,   // y as packed bf16x2
    int n_nodes)
{
    __shared__ float W1s[DIM][DIM];
    __shared__ float W2s[DIM][DIM];
    __shared__ float b2s[DIM];
    __shared__ float xs[8][DIM];

    const int t = threadIdx.x;
    for (int i = t; i < DIM * DIM; i += 256) {
        int c = i >> 5, k = i & 31;
        W1s[k][c] = W1[i];
        W2s[k][c] = W2[i];
    }
    if (t < DIM) b2s[t] = b2[t];

    const int r = t >> 5;
    const int c = t & 31;
    const int ntiles = (n_nodes + 7) >> 3;

    for (int tile = blockIdx.x; tile < ntiles; tile += gridDim.x) {
        const int row = tile * 8 + r;
        __syncthreads();
        if (row < n_nodes) xs[r][c] = x[(long)row * DIM + c];
        __syncthreads();
        if (row < n_nodes) {
            float a2 = b2s[c];
            float a1 = 0.0f;
            #pragma unroll
            for (int k = 0; k < DIM; ++k) {
                float xv = xs[r][k];
                a2 += xv * W2s[k][c];
                a1 += xv * W1s[k][c];
            }
            out[(long)row * DIM + c] = a2;
            float hi = __shfl_down(a1, 1);
            if ((c & 1) == 0) {
                __hip_bfloat16 blo = __float2bfloat16(a1);
                __hip_bfloat16 bhi = __float2bfloat16(hi);
                unsigned pack = ((unsigned)(*(unsigned short*)&bhi) << 16)
                              | (unsigned)(*(unsigned short*)&blo);
                y32[(size_t)row * 16 + (c >> 1)] = pack;
            }
        }
    }
}

__global__ __launch_bounds__(256) void init_cursor_kernel(int* __restrict__ cursor, int nb)
{
    int i = blockIdx.x * 256 + threadIdx.x;
    if (i < nb) cursor[i] = i * CAP;
}

// ---------------------------------------------------------------------------
// Pass 1: bucket scatter with block-level LDS aggregation (782 buckets).
// ---------------------------------------------------------------------------
__global__ __launch_bounds__(256) void bucket_scatter_kernel(
    const int* __restrict__ src, const int* __restrict__ dst,
    int* __restrict__ cursor, unsigned* __restrict__ bedges, int nE)
{
    __shared__ int cnt[NBINS];
    __shared__ int base[NBINS];
    __shared__ int rank[NBINS];

    const int t = threadIdx.x;
    const long blockStart = (long)blockIdx.x * EPB;

    for (int i = t; i < NBINS; i += 256) { cnt[i] = 0; rank[i] = 0; }
    __syncthreads();

    int es[EPT], ed[EPT];
    #pragma unroll
    for (int i = 0; i < EPT; ++i) {
        long e = blockStart + i * 256 + t;
        if (e < nE) { es[i] = src[e]; ed[i] = dst[e]; }
        else        { es[i] = -1;     ed[i] = 0;      }
    }
    #pragma unroll
    for (int i = 0; i < EPT; ++i) {
        if (es[i] >= 0) atomicAdd(&cnt[ed[i] >> LOG_NPB], 1);
    }
    __syncthreads();

    for (int i = t; i < NBINS; i += 256) {
        int c = cnt[i];
        if (c > 0) base[i] = atomicAdd(&cursor[i], c);
    }
    __syncthreads();

    #pragma unroll
    for (int i = 0; i < EPT; ++i) {
        if (es[i] >= 0) {
            int b = ed[i] >> LOG_NPB;
            int r = atomicAdd(&rank[b], 1);
            int p = base[b] + r;
            if (p < (b + 1) * CAP)
                bedges[p] = ((unsigned)es[i] << LOG_NPB) | (unsigned)(ed[i] & (NPB - 1));
        }
    }
}

// ---------------------------------------------------------------------------
// Pass 2: in-bucket sort to node granularity (one block per bucket).
// Emits rowdesc = (start, cnt) per node.
// ---------------------------------------------------------------------------
__global__ __launch_bounds__(256) void bucket_sort_kernel(
    const int* __restrict__ cursor, unsigned* __restrict__ bedges,
    int2* __restrict__ rowdesc, int n_nodes)
{
    __shared__ unsigned ent[CAP];     // 16 KB
    __shared__ int cnt[NPB];
    __shared__ int ex[NPB];
    __shared__ int cur[NPB];

    const int b = blockIdx.x;
    const int t = threadIdx.x;
    const int start = b * CAP;
    int n = cursor[b] - start;
    if (n > CAP) n = CAP;
    if (n < 0) n = 0;

    if (t < NPB) { cnt[t] = 0; cur[t] = 0; }
    __syncthreads();

    for (int i = t; i < n; i += 256) {
        unsigned e = bedges[start + i];
        ent[i] = e;
        atomicAdd(&cnt[e & (NPB - 1)], 1);
    }
    __syncthreads();

    if (t < NPB) ex[t] = cnt[t];
    __syncthreads();
    for (int off = 1; off < NPB; off <<= 1) {
        int add = 0;
        if (t < NPB && t >= off) add = ex[t - off];
        __syncthreads();
        if (t < NPB) ex[t] += add;
        __syncthreads();
    }
    if (t < NPB) ex[t] -= cnt[t];
    __syncthreads();

    for (int i = t; i < n; i += 256) {
        unsigned e = ent[i];
        int bin = (int)(e & (NPB - 1));
        int r = atomicAdd(&cur[bin], 1);
        bedges[start + ex[bin] + r] = e >> LOG_NPB;
    }

    if (t < NPB) {
        int node = b * NPB + t;
        if (node < n_nodes) rowdesc[node] = make_int2(start + ex[t], cnt[t]);
    }
}

// ---------------------------------------------------------------------------
// Pass 3: persistent-wave pipelined gather. One wave per node per step;
// wave grid-strides over nodes, prefetching next node's rowdesc + out row
// while processing the current one. 8 slots x 8 lanes; lane loads ushort4.
// ---------------------------------------------------------------------------
__global__ __launch_bounds__(256) void gather_kernel(
    const int2* __restrict__ rowdesc,
    const unsigned* __restrict__ bedges,
    const unsigned short* __restrict__ yb,
    float* __restrict__ out, int n_nodes, int nwaves)
{
    const int w0   = (blockIdx.x * 256 + threadIdx.x) >> 6;
    const int lane = threadIdx.x & 63;
    const int slot = lane >> 3;   // 0..7: edge slot
    const int li   = lane & 7;    // dims li*4 .. li*4+3

    int node = w0;
    if (node >= n_nodes) return;

    int2   rd = rowdesc[node];
    float4 o  = ((const float4*)(out + ((size_t)node << 5)))[li];

    while (true) {
        const int nx = node + nwaves;
        const bool have_n = nx < n_nodes;
        int2   rd_n;
        float4 o_n;
        if (have_n) {                        // prefetch next node's metadata + out row
            rd_n = rowdesc[nx];
            o_n  = ((const float4*)(out + ((size_t)nx << 5)))[li];
        }

        const int start = rd.x;
        const int end   = start + rd.y;
        float a0 = 0.f, a1 = 0.f, a2 = 0.f, a3 = 0.f;

        for (int e0 = start + slot; e0 < end; e0 += 16) {
            int e1 = e0 + 8;
            int s0 = (int)bedges[e0];
            int s1 = (int)bedges[e1 < end ? e1 : end - 1];   // clamped, unguarded
            ushort4 u0 = *(const ushort4*)(yb + ((size_t)s0 << 5) + (li << 2));
            ushort4 u1 = *(const ushort4*)(yb + ((size_t)s1 << 5) + (li << 2));
            a0 += __uint_as_float((unsigned)u0.x << 16);
            a1 += __uint_as_float((unsigned)u0.y << 16);
            a2 += __uint_as_float((unsigned)u0.z << 16);
            a3 += __uint_as_float((unsigned)u0.w << 16);
            if (e1 < end) {
                a0 += __uint_as_float((unsigned)u1.x << 16);
                a1 += __uint_as_float((unsigned)u1.y << 16);
                a2 += __uint_as_float((unsigned)u1.z << 16);
                a3 += __uint_as_float((unsigned)u1.w << 16);
            }
        }

        #pragma unroll
        for (int m = 8; m < 64; m <<= 1) {
            a0 += __shfl_xor(a0, m);
            a1 += __shfl_xor(a1, m);
            a2 += __shfl_xor(a2, m);
            a3 += __shfl_xor(a3, m);
        }

        if (slot == 0) {
            o.x += a0; o.y += a1; o.z += a2; o.w += a3;
            ((float4*)(out + ((size_t)node << 5)))[li] = o;
        }

        if (!have_n) break;
        node = nx; rd = rd_n; o = o_n;
    }
}

extern "C" void kernel_launch(void* const* d_in, const int* in_sizes, int n_in,
                              void* d_out, int out_size, void* d_ws, size_t ws_size,
                              hipStream_t stream) {
    const float* x  = (const float*)d_in[0];
    const float* W1 = (const float*)d_in[1];
    const float* W2 = (const float*)d_in[2];
    const float* b2 = (const float*)d_in[3];
    const int*   ei = (const int*)d_in[4];

    const int n_nodes = in_sizes[0] / DIM;   // 100000
    const int n_edges = in_sizes[4] / 2;     // 1,600,000
    const int* src = ei;
    const int* dst = ei + n_edges;
    float* out = (float*)d_out;

    const int nb = (n_nodes + NPB - 1) / NPB;    // 782

    char* basep = (char*)d_ws;
    size_t off = 0;
    auto alloc = [&](size_t bytes) {
        char* p = basep + off;
        off = (off + bytes + 255) & ~(size_t)255;
        return p;
    };
    unsigned* y32     = (unsigned*)alloc((size_t)n_nodes * DIM * sizeof(unsigned short));
    int*      cursor  = (int*)     alloc((size_t)nb * sizeof(int));
    unsigned* bedges  = (unsigned*)alloc((size_t)nb * CAP * sizeof(unsigned));
    int2*     rowdesc = (int2*)    alloc((size_t)n_nodes * sizeof(int2));
    (void)ws_size;

    fused_lin_kernel<<<1024, 256, 0, stream>>>(x, W1, W2, b2, out, y32, n_nodes);
    init_cursor_kernel<<<(nb + 255) / 256, 256, 0, stream>>>(cursor, nb);
    bucket_scatter_kernel<<<(n_edges + EPB - 1) / EPB, 256, 0, stream>>>(src, dst, cursor, bedges, n_edges);
    bucket_sort_kernel<<<nb, 256, 0, stream>>>(cursor, bedges, rowdesc, n_nodes);

    const int nwaves = GATHER_BLOCKS * 4;
    gather_kernel<<<GATHER_BLOCKS, 256, 0, stream>>>(rowdesc, bedges,
                                                     (const unsigned short*)y32, out,
                                                     n_nodes, nwaves);
}

// Round 8
// 94.578 us; speedup vs baseline: 1.1619x; 1.0714x over previous
//
#include <hip/hip_runtime.h>
#include <hip/hip_bf16.h>

#define DIM 32
#define LOG_NPB 7
#define NPB 128              // nodes per bucket
#define CAP 4096             // edge capacity per bucket (avg ~2046)
#define NBINS 800            // >= ceil(100000/128)=782
#define EPB 4096             // edges per scatter block
#define EPT 16               // edges per thread in scatter (EPB/256)
#define GATHER_BLOCKS 2048   // persistent gather waves: 2048*4 = 8192

// ---------------------------------------------------------------------------
// Kernel 1: out = x @ W2^T + b2 (fp32) ;  y = x @ W1^T (bf16, packed stores)
// ---------------------------------------------------------------------------
__global__ __launch_bounds__(256) void fused_lin_kernel(
    const float* __restrict__ x,
    const float* __restrict__ W1,
    const float* __restrict__ W2,
    const float* __restrict__ b2,
    float* __restrict__ out,
    unsigned* __restrict__ y32,   // y as packed bf16x2
    int n_nodes)
{
    __shared__ float W1s[DIM][DIM];
    __shared__ float W2s[DIM][DIM];
    __shared__ float b2s[DIM];
    __shared__ float xs[8][DIM];

    const int t = threadIdx.x;
    for (int i = t; i < DIM * DIM; i += 256) {
        int c = i >> 5, k = i & 31;
        W1s[k][c] = W1[i];
        W2s[k][c] = W2[i];
    }
    if (t < DIM) b2s[t] = b2[t];

    const int r = t >> 5;
    const int c = t & 31;
    const int ntiles = (n_nodes + 7) >> 3;

    for (int tile = blockIdx.x; tile < ntiles; tile += gridDim.x) {
        const int row = tile * 8 + r;
        __syncthreads();
        if (row < n_nodes) xs[r][c] = x[(long)row * DIM + c];
        __syncthreads();
        if (row < n_nodes) {
            float a2 = b2s[c];
            float a1 = 0.0f;
            #pragma unroll
            for (int k = 0; k < DIM; ++k) {
                float xv = xs[r][k];
                a2 += xv * W2s[k][c];
                a1 += xv * W1s[k][c];
            }
            out[(long)row * DIM + c] = a2;
            float hi = __shfl_down(a1, 1);
            if ((c & 1) == 0) {
                __hip_bfloat16 blo = __float2bfloat16(a1);
                __hip_bfloat16 bhi = __float2bfloat16(hi);
                unsigned pack = ((unsigned)(*(unsigned short*)&bhi) << 16)
                              | (unsigned)(*(unsigned short*)&blo);
                y32[(size_t)row * 16 + (c >> 1)] = pack;
            }
        }
    }
}

__global__ __launch_bounds__(256) void init_cursor_kernel(int* __restrict__ cursor, int nb)
{
    int i = blockIdx.x * 256 + threadIdx.x;
    if (i < nb) cursor[i] = i * CAP;
}

// ---------------------------------------------------------------------------
// Pass 1: bucket scatter with block-level LDS aggregation (782 buckets).
// ---------------------------------------------------------------------------
__global__ __launch_bounds__(256) void bucket_scatter_kernel(
    const int* __restrict__ src, const int* __restrict__ dst,
    int* __restrict__ cursor, unsigned* __restrict__ bedges, int nE)
{
    __shared__ int cnt[NBINS];
    __shared__ int base[NBINS];
    __shared__ int rank[NBINS];

    const int t = threadIdx.x;
    const long blockStart = (long)blockIdx.x * EPB;

    for (int i = t; i < NBINS; i += 256) { cnt[i] = 0; rank[i] = 0; }
    __syncthreads();

    int es[EPT], ed[EPT];
    #pragma unroll
    for (int i = 0; i < EPT; ++i) {
        long e = blockStart + i * 256 + t;
        if (e < nE) { es[i] = src[e]; ed[i] = dst[e]; }
        else        { es[i] = -1;     ed[i] = 0;      }
    }
    #pragma unroll
    for (int i = 0; i < EPT; ++i) {
        if (es[i] >= 0) atomicAdd(&cnt[ed[i] >> LOG_NPB], 1);
    }
    __syncthreads();

    for (int i = t; i < NBINS; i += 256) {
        int c = cnt[i];
        if (c > 0) base[i] = atomicAdd(&cursor[i], c);
    }
    __syncthreads();

    #pragma unroll
    for (int i = 0; i < EPT; ++i) {
        if (es[i] >= 0) {
            int b = ed[i] >> LOG_NPB;
            int r = atomicAdd(&rank[b], 1);
            int p = base[b] + r;
            if (p < (b + 1) * CAP)
                bedges[p] = ((unsigned)es[i] << LOG_NPB) | (unsigned)(ed[i] & (NPB - 1));
        }
    }
}

// ---------------------------------------------------------------------------
// Pass 2: in-bucket sort to node granularity (one block per bucket).
// Emits rowdesc = (start, cnt) per node.
// ---------------------------------------------------------------------------
__global__ __launch_bounds__(256) void bucket_sort_kernel(
    const int* __restrict__ cursor, unsigned* __restrict__ bedges,
    int2* __restrict__ rowdesc, int n_nodes)
{
    __shared__ unsigned ent[CAP];     // 16 KB
    __shared__ int cnt[NPB];
    __shared__ int ex[NPB];
    __shared__ int cur[NPB];

    const int b = blockIdx.x;
    const int t = threadIdx.x;
    const int start = b * CAP;
    int n = cursor[b] - start;
    if (n > CAP) n = CAP;
    if (n < 0) n = 0;

    if (t < NPB) { cnt[t] = 0; cur[t] = 0; }
    __syncthreads();

    for (int i = t; i < n; i += 256) {
        unsigned e = bedges[start + i];
        ent[i] = e;
        atomicAdd(&cnt[e & (NPB - 1)], 1);
    }
    __syncthreads();

    if (t < NPB) ex[t] = cnt[t];
    __syncthreads();
    for (int off = 1; off < NPB; off <<= 1) {
        int add = 0;
        if (t < NPB && t >= off) add = ex[t - off];
        __syncthreads();
        if (t < NPB) ex[t] += add;
        __syncthreads();
    }
    if (t < NPB) ex[t] -= cnt[t];
    __syncthreads();

    for (int i = t; i < n; i += 256) {
        unsigned e = ent[i];
        int bin = (int)(e & (NPB - 1));
        int r = atomicAdd(&cur[bin], 1);
        bedges[start + ex[bin] + r] = e >> LOG_NPB;
    }

    if (t < NPB) {
        int node = b * NPB + t;
        if (node < n_nodes) rowdesc[node] = make_int2(start + ex[t], cnt[t]);
    }
}

// ---------------------------------------------------------------------------
// Pass 3: persistent-wave gather, 2-stage pipeline:
//   - 32-edge batch per node (4 clamped ushort4 loads/lane, gated adds)
//   - next node's rowdesc + out row + bedges indices prefetched while the
//     current node's y loads are in flight
// 8 slots x 8 lanes; no atomics; rare tail loop for deg > 32.
// ---------------------------------------------------------------------------
__global__ __launch_bounds__(256) void gather_kernel(
    const int2* __restrict__ rowdesc,
    const unsigned* __restrict__ bedges,
    const unsigned short* __restrict__ yb,
    float* __restrict__ out, int n_nodes, int nwaves)
{
    const int w0   = (blockIdx.x * 256 + threadIdx.x) >> 6;
    const int lane = threadIdx.x & 63;
    const int slot = lane >> 3;   // 0..7: edge slot
    const int li   = lane & 7;    // dims li*4 .. li*4+3

    int node = w0;
    if (node >= n_nodes) return;

    // prologue: load first node's state
    int2   rd = rowdesc[node];
    float4 o  = ((const float4*)(out + ((size_t)node << 5)))[li];
    int s[4];
    {
        const int start = rd.x, end = start + rd.y;
        #pragma unroll
        for (int k = 0; k < 4; ++k) {
            int e = start + slot + 8 * k;
            s[k] = (rd.y > 0) ? (int)bedges[e < end ? e : end - 1] : 0;
        }
    }

    while (true) {
        const int nx = node + nwaves;
        const bool have_n = nx < n_nodes;      // wave-uniform
        int2   rd_n;
        float4 o_n;
        int    sn[4];

        if (have_n) {
            rd_n = rowdesc[nx];
            o_n  = ((const float4*)(out + ((size_t)nx << 5)))[li];
        }

        // issue current node's y loads (32 edges in flight)
        const int d     = rd.y;
        const int start = rd.x;
        const int end   = start + d;
        ushort4 u[4];
        #pragma unroll
        for (int k = 0; k < 4; ++k)
            u[k] = *(const ushort4*)(yb + ((size_t)s[k] << 5) + (li << 2));

        // prefetch next node's edge indices while y loads are in flight
        if (have_n) {
            const int st_n = rd_n.x, en_n = st_n + rd_n.y;
            #pragma unroll
            for (int k = 0; k < 4; ++k) {
                int e = st_n + slot + 8 * k;
                sn[k] = (rd_n.y > 0) ? (int)bedges[e < en_n ? e : en_n - 1] : 0;
            }
        }

        float a0 = 0.f, a1 = 0.f, a2 = 0.f, a3 = 0.f;
        #pragma unroll
        for (int k = 0; k < 4; ++k) {
            const bool v = (slot + 8 * k) < d;   // gate clamped duplicates
            a0 += v ? __uint_as_float((unsigned)u[k].x << 16) : 0.f;
            a1 += v ? __uint_as_float((unsigned)u[k].y << 16) : 0.f;
            a2 += v ? __uint_as_float((unsigned)u[k].z << 16) : 0.f;
            a3 += v ? __uint_as_float((unsigned)u[k].w << 16) : 0.f;
        }

        // rare tail: degree > 32 (P ~ 1e-4 for Poisson(16))
        for (int e0 = start + 32 + slot; e0 < end; e0 += 8) {
            int ss = (int)bedges[e0];
            ushort4 uu = *(const ushort4*)(yb + ((size_t)ss << 5) + (li << 2));
            a0 += __uint_as_float((unsigned)uu.x << 16);
            a1 += __uint_as_float((unsigned)uu.y << 16);
            a2 += __uint_as_float((unsigned)uu.z << 16);
            a3 += __uint_as_float((unsigned)uu.w << 16);
        }

        #pragma unroll
        for (int m = 8; m < 64; m <<= 1) {
            a0 += __shfl_xor(a0, m);
            a1 += __shfl_xor(a1, m);
            a2 += __shfl_xor(a2, m);
            a3 += __shfl_xor(a3, m);
        }

        if (slot == 0 && d > 0) {
            o.x += a0; o.y += a1; o.z += a2; o.w += a3;
            ((float4*)(out + ((size_t)node << 5)))[li] = o;
        }

        if (!have_n) break;
        node = nx; rd = rd_n; o = o_n;
        s[0] = sn[0]; s[1] = sn[1]; s[2] = sn[2]; s[3] = sn[3];
    }
}

extern "C" void kernel_launch(void* const* d_in, const int* in_sizes, int n_in,
                              void* d_out, int out_size, void* d_ws, size_t ws_size,
                              hipStream_t stream) {
    const float* x  = (const float*)d_in[0];
    const float* W1 = (const float*)d_in[1];
    const float* W2 = (const float*)d_in[2];
    const float* b2 = (const float*)d_in[3];
    const int*   ei = (const int*)d_in[4];

    const int n_nodes = in_sizes[0] / DIM;   // 100000
    const int n_edges = in_sizes[4] / 2;     // 1,600,000
    const int* src = ei;
    const int* dst = ei + n_edges;
    float* out = (float*)d_out;

    const int nb = (n_nodes + NPB - 1) / NPB;    // 782

    char* basep = (char*)d_ws;
    size_t off = 0;
    auto alloc = [&](size_t bytes) {
        char* p = basep + off;
        off = (off + bytes + 255) & ~(size_t)255;
        return p;
    };
    unsigned* y32     = (unsigned*)alloc((size_t)n_nodes * DIM * sizeof(unsigned short));
    int*      cursor  = (int*)     alloc((size_t)nb * sizeof(int));
    unsigned* bedges  = (unsigned*)alloc((size_t)nb * CAP * sizeof(unsigned));
    int2*     rowdesc = (int2*)    alloc((size_t)n_nodes * sizeof(int2));
    (void)ws_size;

    fused_lin_kernel<<<1024, 256, 0, stream>>>(x, W1, W2, b2, out, y32, n_nodes);
    init_cursor_kernel<<<(nb + 255) / 256, 256, 0, stream>>>(cursor, nb);
    bucket_scatter_kernel<<<(n_edges + EPB - 1) / EPB, 256, 0, stream>>>(src, dst, cursor, bedges, n_edges);
    bucket_sort_kernel<<<nb, 256, 0, stream>>>(cursor, bedges, rowdesc, n_nodes);

    const int nwaves = GATHER_BLOCKS * 4;
    gather_kernel<<<GATHER_BLOCKS, 256, 0, stream>>>(rowdesc, bedges,
                                                     (const unsigned short*)y32, out,
                                                     n_nodes, nwaves);
}

// Round 9
// 86.415 us; speedup vs baseline: 1.2716x; 1.0945x over previous
//
#include <hip/hip_runtime.h>
#include <hip/hip_bf16.h>

#define DIM 32
#define LOG_NPB 7
#define NPB 128              // nodes per bucket
#define CAP 4096             // edge capacity per bucket (avg ~2046)
#define NBINS 800            // >= ceil(100000/128)=782
#define EPB 4096             // edges per scatter block
#define EPT 16               // edges per thread in scatter (EPB/256)

// ---------------------------------------------------------------------------
// Kernel 1: out = x @ W2^T + b2 (fp32) ;  y = x @ W1^T (bf16 packed).
// Block 0 additionally initializes the bucket cursor array.
// ---------------------------------------------------------------------------
__global__ __launch_bounds__(256) void fused_lin_kernel(
    const float* __restrict__ x,
    const float* __restrict__ W1,
    const float* __restrict__ W2,
    const float* __restrict__ b2,
    float* __restrict__ out,
    unsigned* __restrict__ y32,
    int* __restrict__ cursor, int nb,
    int n_nodes)
{
    __shared__ float W1s[DIM][DIM];
    __shared__ float W2s[DIM][DIM];
    __shared__ float b2s[DIM];
    __shared__ float xs[8][DIM];

    const int t = threadIdx.x;

    if (blockIdx.x == 0) {
        for (int i = t; i < nb; i += 256) cursor[i] = i * CAP;
    }

    for (int i = t; i < DIM * DIM; i += 256) {
        int c = i >> 5, k = i & 31;
        W1s[k][c] = W1[i];
        W2s[k][c] = W2[i];
    }
    if (t < DIM) b2s[t] = b2[t];

    const int r = t >> 5;
    const int c = t & 31;
    const int ntiles = (n_nodes + 7) >> 3;

    for (int tile = blockIdx.x; tile < ntiles; tile += gridDim.x) {
        const int row = tile * 8 + r;
        __syncthreads();
        if (row < n_nodes) xs[r][c] = x[(long)row * DIM + c];
        __syncthreads();
        if (row < n_nodes) {
            float a2 = b2s[c];
            float a1 = 0.0f;
            #pragma unroll
            for (int k = 0; k < DIM; ++k) {
                float xv = xs[r][k];
                a2 += xv * W2s[k][c];
                a1 += xv * W1s[k][c];
            }
            out[(long)row * DIM + c] = a2;
            float hi = __shfl_down(a1, 1);
            if ((c & 1) == 0) {
                __hip_bfloat16 blo = __float2bfloat16(a1);
                __hip_bfloat16 bhi = __float2bfloat16(hi);
                unsigned pack = ((unsigned)(*(unsigned short*)&bhi) << 16)
                              | (unsigned)(*(unsigned short*)&blo);
                y32[(size_t)row * 16 + (c >> 1)] = pack;
            }
        }
    }
}

// ---------------------------------------------------------------------------
// Pass 1: bucket scatter with block-level LDS aggregation (782 buckets).
// ---------------------------------------------------------------------------
__global__ __launch_bounds__(256) void bucket_scatter_kernel(
    const int* __restrict__ src, const int* __restrict__ dst,
    int* __restrict__ cursor, unsigned* __restrict__ bedges, int nE)
{
    __shared__ int cnt[NBINS];
    __shared__ int base[NBINS];
    __shared__ int rank[NBINS];

    const int t = threadIdx.x;
    const long blockStart = (long)blockIdx.x * EPB;

    for (int i = t; i < NBINS; i += 256) { cnt[i] = 0; rank[i] = 0; }
    __syncthreads();

    int es[EPT], ed[EPT];
    #pragma unroll
    for (int i = 0; i < EPT; ++i) {
        long e = blockStart + i * 256 + t;
        if (e < nE) { es[i] = src[e]; ed[i] = dst[e]; }
        else        { es[i] = -1;     ed[i] = 0;      }
    }
    #pragma unroll
    for (int i = 0; i < EPT; ++i) {
        if (es[i] >= 0) atomicAdd(&cnt[ed[i] >> LOG_NPB], 1);
    }
    __syncthreads();

    for (int i = t; i < NBINS; i += 256) {
        int c = cnt[i];
        if (c > 0) base[i] = atomicAdd(&cursor[i], c);
    }
    __syncthreads();

    #pragma unroll
    for (int i = 0; i < EPT; ++i) {
        if (es[i] >= 0) {
            int b = ed[i] >> LOG_NPB;
            int r = atomicAdd(&rank[b], 1);
            int p = base[b] + r;
            if (p < (b + 1) * CAP)
                bedges[p] = ((unsigned)es[i] << LOG_NPB) | (unsigned)(ed[i] & (NPB - 1));
        }
    }
}

// ---------------------------------------------------------------------------
// Pass 2 (fused): per-bucket sort in LDS, then gather directly from the
// sorted LDS list. 512 threads = 8 waves; wave w handles local nodes
// w, w+8, ... Each node: 8 slots x 8 lanes, 32-edge clamped batch.
// ---------------------------------------------------------------------------
__global__ __launch_bounds__(512) void sort_gather_kernel(
    const int* __restrict__ cursor, const unsigned* __restrict__ bedges,
    const unsigned short* __restrict__ yb,
    float* __restrict__ out, int n_nodes)
{
    __shared__ unsigned ent[CAP];      // 16 KB raw entries
    __shared__ unsigned sorted[CAP];   // 16 KB src ids sorted by local dst
    __shared__ int cnt[NPB];
    __shared__ int ex[NPB];
    __shared__ int cur[NPB];

    const int b = blockIdx.x;
    const int t = threadIdx.x;
    const int start = b * CAP;
    int n = cursor[b] - start;
    if (n > CAP) n = CAP;
    if (n < 0) n = 0;

    if (t < NPB) { cnt[t] = 0; cur[t] = 0; }
    __syncthreads();

    for (int i = t; i < n; i += 512) {
        unsigned e = bedges[start + i];
        ent[i] = e;
        atomicAdd(&cnt[e & (NPB - 1)], 1);
    }
    __syncthreads();

    if (t < NPB) ex[t] = cnt[t];
    __syncthreads();
    for (int off = 1; off < NPB; off <<= 1) {
        int add = 0;
        if (t < NPB && t >= off) add = ex[t - off];
        __syncthreads();
        if (t < NPB) ex[t] += add;
        __syncthreads();
    }
    if (t < NPB) ex[t] -= cnt[t];
    __syncthreads();

    for (int i = t; i < n; i += 512) {
        unsigned e = ent[i];
        int bin = (int)(e & (NPB - 1));
        int r = atomicAdd(&cur[bin], 1);
        sorted[ex[bin] + r] = e >> LOG_NPB;
    }
    __syncthreads();

    // ---- gather phase ----
    const int wv   = t >> 6;      // wave 0..7
    const int lane = t & 63;
    const int slot = lane >> 3;   // 0..7
    const int li   = lane & 7;    // dims li*4..li*4+3

    for (int ln = wv; ln < NPB; ln += 8) {
        const int node = b * NPB + ln;           // wave-uniform
        if (node >= n_nodes) break;
        const int st = ex[ln];
        const int d  = cnt[ln];
        if (d == 0) continue;

        float a0 = 0.f, a1 = 0.f, a2 = 0.f, a3 = 0.f;

        // 32-edge clamped batch (covers deg <= 32)
        int s[4];
        #pragma unroll
        for (int k = 0; k < 4; ++k) {
            int e = slot + 8 * k;
            s[k] = (int)sorted[st + (e < d ? e : d - 1)];
        }
        ushort4 u[4];
        #pragma unroll
        for (int k = 0; k < 4; ++k)
            u[k] = *(const ushort4*)(yb + ((size_t)s[k] << 5) + (li << 2));
        #pragma unroll
        for (int k = 0; k < 4; ++k) {
            const bool v = (slot + 8 * k) < d;
            a0 += v ? __uint_as_float((unsigned)u[k].x << 16) : 0.f;
            a1 += v ? __uint_as_float((unsigned)u[k].y << 16) : 0.f;
            a2 += v ? __uint_as_float((unsigned)u[k].z << 16) : 0.f;
            a3 += v ? __uint_as_float((unsigned)u[k].w << 16) : 0.f;
        }

        // rare tail: degree > 32
        for (int e0 = 32 + slot; e0 < d; e0 += 8) {
            int ss = (int)sorted[st + e0];
            ushort4 uu = *(const ushort4*)(yb + ((size_t)ss << 5) + (li << 2));
            a0 += __uint_as_float((unsigned)uu.x << 16);
            a1 += __uint_as_float((unsigned)uu.y << 16);
            a2 += __uint_as_float((unsigned)uu.z << 16);
            a3 += __uint_as_float((unsigned)uu.w << 16);
        }

        #pragma unroll
        for (int m = 8; m < 64; m <<= 1) {
            a0 += __shfl_xor(a0, m);
            a1 += __shfl_xor(a1, m);
            a2 += __shfl_xor(a2, m);
            a3 += __shfl_xor(a3, m);
        }

        if (slot == 0) {
            float4* orow = (float4*)(out + ((size_t)node << 5));
            float4 o = orow[li];
            o.x += a0; o.y += a1; o.z += a2; o.w += a3;
            orow[li] = o;
        }
    }
}

extern "C" void kernel_launch(void* const* d_in, const int* in_sizes, int n_in,
                              void* d_out, int out_size, void* d_ws, size_t ws_size,
                              hipStream_t stream) {
    const float* x  = (const float*)d_in[0];
    const float* W1 = (const float*)d_in[1];
    const float* W2 = (const float*)d_in[2];
    const float* b2 = (const float*)d_in[3];
    const int*   ei = (const int*)d_in[4];

    const int n_nodes = in_sizes[0] / DIM;   // 100000
    const int n_edges = in_sizes[4] / 2;     // 1,600,000
    const int* src = ei;
    const int* dst = ei + n_edges;
    float* out = (float*)d_out;

    const int nb = (n_nodes + NPB - 1) / NPB;    // 782

    char* basep = (char*)d_ws;
    size_t off = 0;
    auto alloc = [&](size_t bytes) {
        char* p = basep + off;
        off = (off + bytes + 255) & ~(size_t)255;
        return p;
    };
    unsigned* y32    = (unsigned*)alloc((size_t)n_nodes * DIM * sizeof(unsigned short));
    int*      cursor = (int*)     alloc((size_t)nb * sizeof(int));
    unsigned* bedges = (unsigned*)alloc((size_t)nb * CAP * sizeof(unsigned));
    (void)ws_size;

    fused_lin_kernel<<<1024, 256, 0, stream>>>(x, W1, W2, b2, out, y32, cursor, nb, n_nodes);
    bucket_scatter_kernel<<<(n_edges + EPB - 1) / EPB, 256, 0, stream>>>(src, dst, cursor, bedges, n_edges);
    sort_gather_kernel<<<nb, 512, 0, stream>>>(cursor, bedges, (const unsigned short*)y32, out, n_nodes);
}